// Round 13
// baseline (28.814 us; speedup 1.0000x reference)
//
#include <hip/hip_runtime.h>
#include <hip/hip_bf16.h>
#include <hip/hip_fp16.h>
#include <math.h>

#define BB 32
#define NN 2048
#define BLK 256
#define NQG 4                    // query groups (of 32) per block
#define QB (NQG * 32)            // 128 queries per block
#define NCH (NN / QB)            // 16 query chunks
#define NBLK (2 * BB * NCH)      // 1024 blocks = 4/CU
#define TPW 8                    // j-tiles held in regs at once (32 VGPRs)
#define NROUND 2                 // 2 rounds x 8 tiles = 16 tiles per wave

typedef _Float16 f16x8 __attribute__((ext_vector_type(8)));
typedef float f32x16 __attribute__((ext_vector_type(16)));

__device__ __forceinline__ unsigned pkh2(_Float16 a, _Float16 b) {
  union { _Float16 h[2]; unsigned u; } v;
  v.h[0] = a; v.h[1] = b;
  return v.u;
}

__device__ __forceinline__ f16x8 mkfrag4(uint4 u) {
  union { uint4 q; f16x8 f; } v;
  v.q = u;
  return v.f;
}

__device__ __forceinline__ float min3f(float a, float b, float c) {
  float r;
  asm("v_min3_f32 %0, %1, %2, %3" : "=v"(r) : "v"(a), "v"(b), "v"(c));
  return r;
}

// 17-input min in 8 v_min3_f32.
__device__ __forceinline__ float min17(const f32x16& d, float mn) {
  float t0 = min3f(d[0], d[1], d[2]);
  float t1 = min3f(d[3], d[4], d[5]);
  float t2 = min3f(d[6], d[7], d[8]);
  float t3 = min3f(d[9], d[10], d[11]);
  float t4 = min3f(d[12], d[13], d[14]);
  float u0 = min3f(t0, t1, t2);
  float u1 = min3f(t3, t4, d[15]);
  return min3f(u0, u1, mn);
}

// Register-resident chamfer, SPLIT-FP16 precision (R12 compute, verbatim),
// plus single-node last-block gather:
//   producer: bsum[bid] = s; threadfence; old = atomicAdd(cnt, 1)
//   last block (old & (NBLK-1) == NBLK-1): volatile-read all 1024 partials
//   in FIXED order, reduce, write out[0]. Wrap-counter is poison-robust:
//   each call adds exactly NBLK; 2^32 % NBLK == 0 -> exactly one trigger
//   per call for any initial value; no reset, no memset, deterministic.
__global__ __launch_bounds__(BLK, 4) void cham_fused(
    const float* __restrict__ est, const float* __restrict__ gt,
    const float* __restrict__ lest, const float* __restrict__ lab,
    float* __restrict__ bsum, unsigned* __restrict__ cnt,
    float* __restrict__ out) {
  int id = blockIdx.x;
  int qc = id % NCH; id /= NCH;
  int b = id % BB;
  int dir = id / BB;

  const float* X = dir ? gt : est;   // queries
  const float* Y = dir ? est : gt;   // targets

  __shared__ uint4 sbq4[QB];               // 2 KB packed hi/lo B data
  __shared__ float partial[4][NQG][32];    // 2 KB per-wave mins

  int tid = threadIdx.x;
  int lane = tid & 63, w = tid >> 6, l31 = lane & 31;
  bool hi = (lane >= 32);
  int qbase = qc * QB;

  // stage this block's 128 queries (thread tid <-> query qbase+tid, tid<QB)
  float x0 = 0.0f, x1 = 0.0f, x2 = 0.0f;
  if (tid < QB) {
    const float* xq = X + ((size_t)b * NN + qbase + tid) * 3;
    x0 = xq[0]; x1 = xq[1]; x2 = xq[2];
    float nx0 = -x0, nx1 = -x1, nx2 = -x2;
    _Float16 x0h = (_Float16)nx0, x1h = (_Float16)nx1, x2h = (_Float16)nx2;
    _Float16 x0l = (_Float16)(nx0 - (float)x0h);
    _Float16 x1l = (_Float16)(nx1 - (float)x1h);
    _Float16 x2l = (_Float16)(nx2 - (float)x2h);
    uint4 q;
    q.x = pkh2(x0h, x1h);
    q.y = pkh2(x2h, (_Float16)1.0f);
    q.z = pkh2(x0l, x1l);
    q.w = pkh2(x2l, (_Float16)0.0f);
    sbq4[tid] = q;
  }
  __syncthreads();

  // hoist: build this lane's 4 B-frags once (16 VGPRs)
  f16x8 BF[NQG];
#pragma unroll
  for (int n = 0; n < NQG; ++n) {
    uint4 u = sbq4[n * 32 + l31];
    uint4 ub;
    ub.x = hi ? u.z : u.x;
    ub.y = hi ? u.w : u.y;
    ub.z = hi ? 0u : u.x;
    ub.w = hi ? 0u : u.y;
    BF[n] = mkfrag4(ub);
  }

  const f32x16 zz = {0.f, 0.f, 0.f, 0.f, 0.f, 0.f, 0.f, 0.f,
                     0.f, 0.f, 0.f, 0.f, 0.f, 0.f, 0.f, 0.f};
  float mall[NQG];
#pragma unroll
  for (int n = 0; n < NQG; ++n) mall[n] = 3.4e38f;

  for (int r = 0; r < NROUND; ++r) {
    // load this round's 8 A-frags (L2-hot), split hi/lo
    f16x8 A[TPW];
#pragma unroll
    for (int k = 0; k < TPW; ++k) {
      int j = (w + 4 * (r * TPW + k)) * 32 + l31;
      const float* yp = Y + ((size_t)b * NN + j) * 3;
      float y0 = yp[0], y1 = yp[1], y2 = yp[2];
      float hv = 0.5f * (y0 * y0 + y1 * y1 + y2 * y2);
      _Float16 y0h = (_Float16)y0, y1h = (_Float16)y1, y2h = (_Float16)y2;
      _Float16 hhh = (_Float16)hv;
      _Float16 y0l = (_Float16)(y0 - (float)y0h);
      _Float16 y1l = (_Float16)(y1 - (float)y1h);
      _Float16 y2l = (_Float16)(y2 - (float)y2h);
      _Float16 hll = (_Float16)(hv - (float)hhh);
      uint4 ua;
      ua.x = pkh2(y0h, y1h);
      ua.y = hi ? pkh2(y2h, (_Float16)0.0f) : pkh2(y2h, hhh);
      ua.z = hi ? 0u : pkh2(y0l, y1l);
      ua.w = hi ? 0u : pkh2(y2l, hll);
      A[k] = mkfrag4(ua);
    }

#pragma unroll
    for (int n = 0; n < NQG; ++n) {
      f16x8 bf = BF[n];
      float m0 = 3.4e38f, m1 = 3.4e38f;
      __builtin_amdgcn_s_setprio(1);
#pragma unroll
      for (int t = 0; t < TPW; t += 2) {
        f32x16 d0 = __builtin_amdgcn_mfma_f32_32x32x16_f16(A[t + 0], bf, zz, 0, 0, 0);
        f32x16 d1 = __builtin_amdgcn_mfma_f32_32x32x16_f16(A[t + 1], bf, zz, 0, 0, 0);
        m0 = min17(d0, m0);
        m1 = min17(d1, m1);
      }
      __builtin_amdgcn_s_setprio(0);
      mall[n] = min3f(mall[n], m0, m1);
    }
  }

  // fold lane halves and publish per-wave mins
#pragma unroll
  for (int n = 0; n < NQG; ++n) {
    float m = mall[n];
    m = fminf(m, __shfl_xor(m, 32, 64));  // merge row halves
    if (lane < 32) partial[w][n][l31] = m;
  }
  __syncthreads();

  // epilogue: thread tid <-> query qbase+tid (tid < QB)
  float val = 0.0f;
  if (tid < QB) {
    int n = tid >> 5, col = tid & 31;
    float m = fminf(fminf(partial[0][n][col], partial[1][n][col]),
                    fminf(partial[2][n][col], partial[3][n][col]));
    float x2n = fmaf(x0, x0, fmaf(x1, x1, x2 * x2));
    val = fmaxf(fmaf(2.0f, m, x2n), 0.0f);   // d2 = x^2 + 2*min D
    if (!dir) {  // fuse BCE for (b, qbase+tid)
      float z = lest[(size_t)b * NN + qbase + tid];
      float t = lab[(size_t)b * NN + qbase + tid];
      val += fmaxf(z, 0.0f) - z * t + log1pf(expf(-fabsf(z)));
    }
  }

  for (int off = 32; off > 0; off >>= 1) val += __shfl_down(val, off);
  __shared__ float wsum[BLK / 64];
  if (lane == 0) wsum[w] = val;
  __syncthreads();

  __shared__ int islast;
  if (tid == 0) {
    float s = wsum[0] + wsum[1] + wsum[2] + wsum[3];
    bsum[blockIdx.x] = s;
    __threadfence();
    unsigned old = atomicAdd(cnt, 1u);
    islast = ((old & (NBLK - 1)) == (NBLK - 1)) ? 1 : 0;
  }
  __syncthreads();

  if (islast) {
    // all 1024 producer adds happened-before our ticket -> partials visible.
    __threadfence();
    const volatile float* vb = (const volatile float*)bsum;
    float acc = 0.0f;
#pragma unroll
    for (int k = 0; k < NBLK / BLK; ++k) acc += vb[tid + k * BLK];
    for (int off = 32; off > 0; off >>= 1) acc += __shfl_down(acc, off);
    __shared__ float csum[BLK / 64];
    if (lane == 0) csum[w] = acc;
    __syncthreads();
    if (tid == 0)
      out[0] = (csum[0] + csum[1] + csum[2] + csum[3]) *
               (1.0f / ((float)BB * (float)NN));
  }
}

// Fallback (proven-correct R1 kernel) if ws is too small.
__global__ __launch_bounds__(BLK) void chamfer_bce_kernel(
    const float* __restrict__ est, const float* __restrict__ gt,
    const float* __restrict__ lest, const float* __restrict__ lab,
    float* __restrict__ out) {
  int bid = blockIdx.x;
  int dir = (bid >= BB * (NN / BLK)) ? 1 : 0;
  int id = dir ? (bid - BB * (NN / BLK)) : bid;
  int b = id / (NN / BLK);
  int tile = id % (NN / BLK);
  const float* X = dir ? gt : est;
  const float* Y = dir ? est : gt;
  __shared__ float4 sy[NN];
  const float* yb = Y + (size_t)b * NN * 3;
  for (int j = threadIdx.x; j < NN; j += BLK)
    sy[j] = make_float4(yb[3 * j], yb[3 * j + 1], yb[3 * j + 2], 0.0f);
  __syncthreads();
  int i = tile * BLK + threadIdx.x;
  const float* xb = X + (size_t)b * NN * 3 + (size_t)3 * i;
  float ex = xb[0], ey = xb[1], ez = xb[2];
  float m0 = 3.4e38f, m1 = 3.4e38f, m2 = 3.4e38f, m3 = 3.4e38f;
#pragma unroll 4
  for (int j = 0; j < NN; j += 4) {
    float4 p0 = sy[j], p1 = sy[j + 1], p2 = sy[j + 2], p3 = sy[j + 3];
    { float dx = ex - p0.x, dy = ey - p0.y, dz = ez - p0.z;
      m0 = fminf(m0, fmaf(dx, dx, fmaf(dy, dy, dz * dz))); }
    { float dx = ex - p1.x, dy = ey - p1.y, dz = ez - p1.z;
      m1 = fminf(m1, fmaf(dx, dx, fmaf(dy, dy, dz * dz))); }
    { float dx = ex - p2.x, dy = ey - p2.y, dz = ez - p2.z;
      m2 = fminf(m2, fmaf(dx, dx, fmaf(dy, dy, dz * dz))); }
    { float dx = ex - p3.x, dy = ey - p3.y, dz = ez - p3.z;
      m3 = fminf(m3, fmaf(dx, dx, fmaf(dy, dy, dz * dz))); }
  }
  float val = fminf(fminf(m0, m1), fminf(m2, m3));
  if (!dir) {
    float z = lest[(size_t)b * NN + i];
    float t = lab[(size_t)b * NN + i];
    val += fmaxf(z, 0.0f) - z * t + log1pf(expf(-fabsf(z)));
  }
  for (int off = 32; off > 0; off >>= 1) val += __shfl_down(val, off);
  __shared__ float wsum[BLK / 64];
  int lane = threadIdx.x & 63;
  int wid = threadIdx.x >> 6;
  if (lane == 0) wsum[wid] = val;
  __syncthreads();
  if (threadIdx.x == 0) {
    float s = 0.0f;
#pragma unroll
    for (int w = 0; w < BLK / 64; ++w) s += wsum[w];
    atomicAdd(out, s * (1.0f / ((float)BB * (float)NN)));
  }
}

extern "C" void kernel_launch(void* const* d_in, const int* in_sizes, int n_in,
                              void* d_out, int out_size, void* d_ws, size_t ws_size,
                              hipStream_t stream) {
  const float* est = (const float*)d_in[0];
  const float* gt = (const float*)d_in[1];
  const float* lest = (const float*)d_in[2];
  const float* lab = (const float*)d_in[3];
  float* out = (float*)d_out;

  const size_t need = (size_t)NBLK * sizeof(float) + sizeof(unsigned);
  if (ws_size >= need) {
    float* bsum = (float*)d_ws;
    unsigned* cnt = (unsigned*)((char*)d_ws + NBLK * sizeof(float));
    cham_fused<<<dim3(NBLK), dim3(BLK), 0, stream>>>(est, gt, lest, lab,
                                                     bsum, cnt, out);
  } else {
    hipMemsetAsync(out, 0, sizeof(float), stream);
    chamfer_bce_kernel<<<dim3(2 * BB * (NN / BLK)), dim3(BLK), 0, stream>>>(
        est, gt, lest, lab, out);
  }
}

// Round 16
// 18.128 us; speedup vs baseline: 1.5895x; 1.5895x over previous
//
#include <hip/hip_runtime.h>
#include <hip/hip_bf16.h>
#include <hip/hip_fp16.h>
#include <math.h>

#define BB 32
#define NN 2048
#define BLK 256
#define NQG 4                    // query groups (of 32) per block
#define QB (NQG * 32)            // 128 queries per block
#define NCH (NN / QB)            // 16 query chunks
#define NBLK (2 * BB * NCH)      // 1024 blocks = 4/CU
#define TPW 8                    // j-tiles held in regs at once (32 VGPRs)
#define NROUND 2                 // 2 rounds x 8 tiles = 16 tiles per wave

typedef _Float16 f16x8 __attribute__((ext_vector_type(8)));
typedef float f32x16 __attribute__((ext_vector_type(16)));

__device__ __forceinline__ unsigned pkh2(_Float16 a, _Float16 b) {
  union { _Float16 h[2]; unsigned u; } v;
  v.h[0] = a; v.h[1] = b;
  return v.u;
}

__device__ __forceinline__ f16x8 mkfrag4(uint4 u) {
  union { uint4 q; f16x8 f; } v;
  v.q = u;
  return v.f;
}

__device__ __forceinline__ float min3f(float a, float b, float c) {
  float r;
  asm("v_min3_f32 %0, %1, %2, %3" : "=v"(r) : "v"(a), "v"(b), "v"(c));
  return r;
}

// 17-input min in 8 v_min3_f32.
__device__ __forceinline__ float min17(const f32x16& d, float mn) {
  float t0 = min3f(d[0], d[1], d[2]);
  float t1 = min3f(d[3], d[4], d[5]);
  float t2 = min3f(d[6], d[7], d[8]);
  float t3 = min3f(d[9], d[10], d[11]);
  float t4 = min3f(d[12], d[13], d[14]);
  float u0 = min3f(t0, t1, t2);
  float u1 = min3f(t3, t4, d[15]);
  return min3f(u0, u1, mn);
}

// Register-resident chamfer, SPLIT-FP16 precision (R12 exact revert — the
// proven config: passed R11/R12/R13 with absmax 0.0117, RNE splits).
// A k0-7: [y0h,y1h,y2h,hh, y0l,y1l,y2l,hl]; k8-15: [y0h,y1h,y2h,0, 0,0,0,0]
// B k0-7: [-x0h,-x1h,-x2h,1, -x0h,-x1h,-x2h,1]; k8-15: [-x0l,-x1l,-x2l,0,..0]
// D = h - xh.yh - xh.yl - xl.yh  (= |y|^2/2 - x.y up to ~1e-6)
// d2 = x^2(f32) + 2*min_j D.
__global__ __launch_bounds__(BLK, 4) void cham_fused(
    const float* __restrict__ est, const float* __restrict__ gt,
    const float* __restrict__ lest, const float* __restrict__ lab,
    float* __restrict__ bsum) {
  int id = blockIdx.x;
  int qc = id % NCH; id /= NCH;
  int b = id % BB;
  int dir = id / BB;

  const float* X = dir ? gt : est;   // queries
  const float* Y = dir ? est : gt;   // targets

  __shared__ uint4 sbq4[QB];               // 2 KB packed hi/lo B data
  __shared__ float partial[4][NQG][32];    // 2 KB per-wave mins

  int tid = threadIdx.x;
  int lane = tid & 63, w = tid >> 6, l31 = lane & 31;
  bool hi = (lane >= 32);
  int qbase = qc * QB;

  // stage this block's 128 queries (thread tid <-> query qbase+tid, tid<QB)
  float x0 = 0.0f, x1 = 0.0f, x2 = 0.0f;
  if (tid < QB) {
    const float* xq = X + ((size_t)b * NN + qbase + tid) * 3;
    x0 = xq[0]; x1 = xq[1]; x2 = xq[2];
    float nx0 = -x0, nx1 = -x1, nx2 = -x2;
    _Float16 x0h = (_Float16)nx0, x1h = (_Float16)nx1, x2h = (_Float16)nx2;
    _Float16 x0l = (_Float16)(nx0 - (float)x0h);
    _Float16 x1l = (_Float16)(nx1 - (float)x1h);
    _Float16 x2l = (_Float16)(nx2 - (float)x2h);
    uint4 q;
    q.x = pkh2(x0h, x1h);
    q.y = pkh2(x2h, (_Float16)1.0f);
    q.z = pkh2(x0l, x1l);
    q.w = pkh2(x2l, (_Float16)0.0f);
    sbq4[tid] = q;
  }
  __syncthreads();

  // hoist: build this lane's 4 B-frags once (16 VGPRs)
  f16x8 BF[NQG];
#pragma unroll
  for (int n = 0; n < NQG; ++n) {
    uint4 u = sbq4[n * 32 + l31];
    uint4 ub;
    ub.x = hi ? u.z : u.x;
    ub.y = hi ? u.w : u.y;
    ub.z = hi ? 0u : u.x;
    ub.w = hi ? 0u : u.y;
    BF[n] = mkfrag4(ub);
  }

  const f32x16 zz = {0.f, 0.f, 0.f, 0.f, 0.f, 0.f, 0.f, 0.f,
                     0.f, 0.f, 0.f, 0.f, 0.f, 0.f, 0.f, 0.f};
  float mall[NQG];
#pragma unroll
  for (int n = 0; n < NQG; ++n) mall[n] = 3.4e38f;

  for (int r = 0; r < NROUND; ++r) {
    // load this round's 8 A-frags (L2-hot), split hi/lo
    f16x8 A[TPW];
#pragma unroll
    for (int k = 0; k < TPW; ++k) {
      int j = (w + 4 * (r * TPW + k)) * 32 + l31;
      const float* yp = Y + ((size_t)b * NN + j) * 3;
      float y0 = yp[0], y1 = yp[1], y2 = yp[2];
      float hv = 0.5f * (y0 * y0 + y1 * y1 + y2 * y2);
      _Float16 y0h = (_Float16)y0, y1h = (_Float16)y1, y2h = (_Float16)y2;
      _Float16 hhh = (_Float16)hv;
      _Float16 y0l = (_Float16)(y0 - (float)y0h);
      _Float16 y1l = (_Float16)(y1 - (float)y1h);
      _Float16 y2l = (_Float16)(y2 - (float)y2h);
      _Float16 hll = (_Float16)(hv - (float)hhh);
      uint4 ua;
      ua.x = pkh2(y0h, y1h);
      ua.y = hi ? pkh2(y2h, (_Float16)0.0f) : pkh2(y2h, hhh);
      ua.z = hi ? 0u : pkh2(y0l, y1l);
      ua.w = hi ? 0u : pkh2(y2l, hll);
      A[k] = mkfrag4(ua);
    }

#pragma unroll
    for (int n = 0; n < NQG; ++n) {
      f16x8 bf = BF[n];
      float m0 = 3.4e38f, m1 = 3.4e38f;
      __builtin_amdgcn_s_setprio(1);
#pragma unroll
      for (int t = 0; t < TPW; t += 2) {
        f32x16 d0 = __builtin_amdgcn_mfma_f32_32x32x16_f16(A[t + 0], bf, zz, 0, 0, 0);
        f32x16 d1 = __builtin_amdgcn_mfma_f32_32x32x16_f16(A[t + 1], bf, zz, 0, 0, 0);
        m0 = min17(d0, m0);
        m1 = min17(d1, m1);
      }
      __builtin_amdgcn_s_setprio(0);
      mall[n] = min3f(mall[n], m0, m1);
    }
  }

  // fold lane halves and publish per-wave mins
#pragma unroll
  for (int n = 0; n < NQG; ++n) {
    float m = mall[n];
    m = fminf(m, __shfl_xor(m, 32, 64));  // merge row halves
    if (lane < 32) partial[w][n][l31] = m;
  }
  __syncthreads();

  // epilogue: thread tid <-> query qbase+tid (tid < QB)
  float val = 0.0f;
  if (tid < QB) {
    int n = tid >> 5, col = tid & 31;
    float m = fminf(fminf(partial[0][n][col], partial[1][n][col]),
                    fminf(partial[2][n][col], partial[3][n][col]));
    float x2n = fmaf(x0, x0, fmaf(x1, x1, x2 * x2));
    val = fmaxf(fmaf(2.0f, m, x2n), 0.0f);   // d2 = x^2 + 2*min D
    if (!dir) {  // fuse BCE for (b, qbase+tid)
      float z = lest[(size_t)b * NN + qbase + tid];
      float t = lab[(size_t)b * NN + qbase + tid];
      val += fmaxf(z, 0.0f) - z * t + log1pf(expf(-fabsf(z)));
    }
  }

  for (int off = 32; off > 0; off >>= 1) val += __shfl_down(val, off);
  __shared__ float wsum[BLK / 64];
  if (lane == 0) wsum[w] = val;
  __syncthreads();
  if (tid == 0)
    bsum[blockIdx.x] = wsum[0] + wsum[1] + wsum[2] + wsum[3];
}

// Final: sum 1024 block partials, scale, store scalar. Deterministic.
__global__ __launch_bounds__(BLK) void sum_kernel(
    const float* __restrict__ bsum, float* __restrict__ out) {
  float val = 0.0f;
#pragma unroll
  for (int k = 0; k < NBLK / BLK; ++k) val += bsum[threadIdx.x + k * BLK];
  for (int off = 32; off > 0; off >>= 1) val += __shfl_down(val, off);
  __shared__ float wsum[BLK / 64];
  int lane = threadIdx.x & 63;
  int wid = threadIdx.x >> 6;
  if (lane == 0) wsum[wid] = val;
  __syncthreads();
  if (threadIdx.x == 0) {
    float s = 0.0f;
#pragma unroll
    for (int wv = 0; wv < BLK / 64; ++wv) s += wsum[wv];
    out[0] = s * (1.0f / ((float)BB * (float)NN));
  }
}

// Fallback (proven-correct R1 kernel) if ws is too small.
__global__ __launch_bounds__(BLK) void chamfer_bce_kernel(
    const float* __restrict__ est, const float* __restrict__ gt,
    const float* __restrict__ lest, const float* __restrict__ lab,
    float* __restrict__ out) {
  int bid = blockIdx.x;
  int dir = (bid >= BB * (NN / BLK)) ? 1 : 0;
  int id = dir ? (bid - BB * (NN / BLK)) : bid;
  int b = id / (NN / BLK);
  int tile = id % (NN / BLK);
  const float* X = dir ? gt : est;
  const float* Y = dir ? est : gt;
  __shared__ float4 sy[NN];
  const float* yb = Y + (size_t)b * NN * 3;
  for (int j = threadIdx.x; j < NN; j += BLK)
    sy[j] = make_float4(yb[3 * j], yb[3 * j + 1], yb[3 * j + 2], 0.0f);
  __syncthreads();
  int i = tile * BLK + threadIdx.x;
  const float* xb = X + (size_t)b * NN * 3 + (size_t)3 * i;
  float ex = xb[0], ey = xb[1], ez = xb[2];
  float m0 = 3.4e38f, m1 = 3.4e38f, m2 = 3.4e38f, m3 = 3.4e38f;
#pragma unroll 4
  for (int j = 0; j < NN; j += 4) {
    float4 p0 = sy[j], p1 = sy[j + 1], p2 = sy[j + 2], p3 = sy[j + 3];
    { float dx = ex - p0.x, dy = ey - p0.y, dz = ez - p0.z;
      m0 = fminf(m0, fmaf(dx, dx, fmaf(dy, dy, dz * dz))); }
    { float dx = ex - p1.x, dy = ey - p1.y, dz = ez - p1.z;
      m1 = fminf(m1, fmaf(dx, dx, fmaf(dy, dy, dz * dz))); }
    { float dx = ex - p2.x, dy = ey - p2.y, dz = ez - p2.z;
      m2 = fminf(m2, fmaf(dx, dx, fmaf(dy, dy, dz * dz))); }
    { float dx = ex - p3.x, dy = ey - p3.y, dz = ez - p3.z;
      m3 = fminf(m3, fmaf(dx, dx, fmaf(dy, dy, dz * dz))); }
  }
  float val = fminf(fminf(m0, m1), fminf(m2, m3));
  if (!dir) {
    float z = lest[(size_t)b * NN + i];
    float t = lab[(size_t)b * NN + i];
    val += fmaxf(z, 0.0f) - z * t + log1pf(expf(-fabsf(z)));
  }
  for (int off = 32; off > 0; off >>= 1) val += __shfl_down(val, off);
  __shared__ float wsum[BLK / 64];
  int lane = threadIdx.x & 63;
  int wid = threadIdx.x >> 6;
  if (lane == 0) wsum[wid] = val;
  __syncthreads();
  if (threadIdx.x == 0) {
    float s = 0.0f;
#pragma unroll
    for (int w = 0; w < BLK / 64; ++w) s += wsum[w];
    atomicAdd(out, s * (1.0f / ((float)BB * (float)NN)));
  }
}

extern "C" void kernel_launch(void* const* d_in, const int* in_sizes, int n_in,
                              void* d_out, int out_size, void* d_ws, size_t ws_size,
                              hipStream_t stream) {
  const float* est = (const float*)d_in[0];
  const float* gt = (const float*)d_in[1];
  const float* lest = (const float*)d_in[2];
  const float* lab = (const float*)d_in[3];
  float* out = (float*)d_out;

  const size_t need = (size_t)NBLK * sizeof(float);  // 4 KB
  if (ws_size >= need) {
    float* bsum = (float*)d_ws;
    cham_fused<<<dim3(NBLK), dim3(BLK), 0, stream>>>(est, gt, lest, lab, bsum);
    sum_kernel<<<dim3(1), dim3(BLK), 0, stream>>>(bsum, out);
  } else {
    (void)hipMemsetAsync(out, 0, sizeof(float), stream);
    chamfer_bce_kernel<<<dim3(2 * BB * (NN / BLK)), dim3(BLK), 0, stream>>>(
        est, gt, lest, lab, out);
  }
}

// Round 17
// 16.633 us; speedup vs baseline: 1.7323x; 1.0899x over previous
//
#include <hip/hip_runtime.h>
#include <hip/hip_bf16.h>
#include <hip/hip_fp16.h>
#include <math.h>

#define BB 32
#define NN 2048
#define BLK 256
#define NQG 4                    // query groups (of 32) per block
#define QB (NQG * 32)            // 128 queries per block
#define NCH (NN / QB)            // 16 query chunks
#define NBLK (2 * BB * NCH)      // 1024 blocks = 4/CU
#define TPW 8                    // j-tiles held in regs at once (32 VGPRs)
#define NROUND 2                 // 2 rounds x 8 tiles = 16 tiles per wave

typedef _Float16 f16x8 __attribute__((ext_vector_type(8)));
typedef float f32x16 __attribute__((ext_vector_type(16)));

__device__ __forceinline__ unsigned pk2h(float a, float b) {
  union { _Float16 h[2]; unsigned u; } v;
  v.h[0] = (_Float16)a; v.h[1] = (_Float16)b;
  return v.u;
}

__device__ __forceinline__ f16x8 mkfrag(unsigned a, unsigned b) {
  union { unsigned u[4]; f16x8 f; } v;
  v.u[0] = a; v.u[1] = b; v.u[2] = 0u; v.u[3] = 0u;
  return v.f;
}

__device__ __forceinline__ float min3f(float a, float b, float c) {
  float r;
  asm("v_min3_f32 %0, %1, %2, %3" : "=v"(r) : "v"(a), "v"(b), "v"(c));
  return r;
}

// 17-input min in 8 v_min3_f32.
__device__ __forceinline__ float min17(const f32x16& d, float mn) {
  float t0 = min3f(d[0], d[1], d[2]);
  float t1 = min3f(d[3], d[4], d[5]);
  float t2 = min3f(d[6], d[7], d[8]);
  float t3 = min3f(d[9], d[10], d[11]);
  float t4 = min3f(d[12], d[13], d[14]);
  float u0 = min3f(t0, t1, t2);
  float u1 = min3f(t3, t4, d[15]);
  return min3f(u0, u1, mn);
}

// Register-resident chamfer — R10's measured-passing compute (duplicated
// fp16 halves: A = [y0,y1,y2,|y|^2/2] both k-halves, B = [-x0,-x1,-x2,1]
// both k-halves -> D = |y|^2 - 2 x.y), with two BIT-IDENTICAL scheduling
// fixes from R12: B-frags hoisted out of the (r,n) loop, and the cross-
// round min kept in registers (min is exact -> same scalar bits as R10,
// which passed with absmax 0.015625 <= 1 bf16 ulp, deterministic).
__global__ __launch_bounds__(BLK, 4) void cham_fused(
    const float* __restrict__ est, const float* __restrict__ gt,
    const float* __restrict__ lest, const float* __restrict__ lab,
    float* __restrict__ bsum) {
  int id = blockIdx.x;
  int qc = id % NCH; id /= NCH;
  int b = id % BB;
  int dir = id / BB;

  const float* X = dir ? gt : est;   // queries
  const float* Y = dir ? est : gt;   // targets

  __shared__ unsigned long long sbq[QB];   // 1 KB packed B-frags
  __shared__ float partial[4][NQG][32];    // 2 KB per-wave mins

  int tid = threadIdx.x;
  int lane = tid & 63, w = tid >> 6, l31 = lane & 31;
  int qbase = qc * QB;

  // stage this block's 128 queries (thread tid <-> query qbase+tid, tid<QB)
  float x0 = 0.0f, x1 = 0.0f, x2 = 0.0f;
  if (tid < QB) {
    const float* xq = X + ((size_t)b * NN + qbase + tid) * 3;
    x0 = xq[0]; x1 = xq[1]; x2 = xq[2];
    union { unsigned u[2]; unsigned long long ull; } pb;
    pb.u[0] = pk2h(-x0, -x1);
    pb.u[1] = pk2h(-x2, 1.0f);
    sbq[tid] = pb.ull;
  }
  __syncthreads();

  // hoist: build this lane's 4 B-frags once
  f16x8 BF[NQG];
#pragma unroll
  for (int n = 0; n < NQG; ++n) {
    union { unsigned long long ull; unsigned u[2]; } qb;
    qb.ull = sbq[n * 32 + l31];
    BF[n] = mkfrag(qb.u[0], qb.u[1]);
  }

  const f32x16 zz = {0.f, 0.f, 0.f, 0.f, 0.f, 0.f, 0.f, 0.f,
                     0.f, 0.f, 0.f, 0.f, 0.f, 0.f, 0.f, 0.f};
  float mall[NQG];
#pragma unroll
  for (int n = 0; n < NQG; ++n) mall[n] = 3.4e38f;

  for (int r = 0; r < NROUND; ++r) {
    // load this round's 8 A-frags (L2-hot)
    f16x8 A[TPW];
#pragma unroll
    for (int k = 0; k < TPW; ++k) {
      int j = (w + 4 * (r * TPW + k)) * 32 + l31;
      const float* yp = Y + ((size_t)b * NN + j) * 3;
      float y0 = yp[0], y1 = yp[1], y2 = yp[2];
      float h = 0.5f * (y0 * y0 + y1 * y1 + y2 * y2);
      A[k] = mkfrag(pk2h(y0, y1), pk2h(y2, h));
    }

#pragma unroll
    for (int n = 0; n < NQG; ++n) {
      f16x8 bf = BF[n];
      float m0 = 3.4e38f, m1 = 3.4e38f;
      __builtin_amdgcn_s_setprio(1);
#pragma unroll
      for (int t = 0; t < TPW; t += 2) {
        f32x16 d0 = __builtin_amdgcn_mfma_f32_32x32x16_f16(A[t + 0], bf, zz, 0, 0, 0);
        f32x16 d1 = __builtin_amdgcn_mfma_f32_32x32x16_f16(A[t + 1], bf, zz, 0, 0, 0);
        m0 = min17(d0, m0);
        m1 = min17(d1, m1);
      }
      __builtin_amdgcn_s_setprio(0);
      mall[n] = min3f(mall[n], m0, m1);
    }
  }

  // fold lane halves and publish per-wave mins
#pragma unroll
  for (int n = 0; n < NQG; ++n) {
    float m = mall[n];
    m = fminf(m, __shfl_xor(m, 32, 64));  // merge row halves
    if (lane < 32) partial[w][n][l31] = m;
  }
  __syncthreads();

  // epilogue: thread tid <-> query qbase+tid (tid < QB)
  float val = 0.0f;
  if (tid < QB) {
    int n = tid >> 5, col = tid & 31;
    float m = fminf(fminf(partial[0][n][col], partial[1][n][col]),
                    fminf(partial[2][n][col], partial[3][n][col]));
    float x2n = fmaf(x0, x0, fmaf(x1, x1, x2 * x2));
    val = fmaxf(x2n + m, 0.0f);              // d2 = x^2 + min(|y|^2 - 2x.y)
    if (!dir) {  // fuse BCE for (b, qbase+tid)
      float z = lest[(size_t)b * NN + qbase + tid];
      float t = lab[(size_t)b * NN + qbase + tid];
      val += fmaxf(z, 0.0f) - z * t + log1pf(expf(-fabsf(z)));
    }
  }

  for (int off = 32; off > 0; off >>= 1) val += __shfl_down(val, off);
  __shared__ float wsum[BLK / 64];
  if (lane == 0) wsum[w] = val;
  __syncthreads();
  if (tid == 0)
    bsum[blockIdx.x] = wsum[0] + wsum[1] + wsum[2] + wsum[3];
}

// Final: sum 1024 block partials, scale, store scalar. Deterministic.
__global__ __launch_bounds__(BLK) void sum_kernel(
    const float* __restrict__ bsum, float* __restrict__ out) {
  float val = 0.0f;
#pragma unroll
  for (int k = 0; k < NBLK / BLK; ++k) val += bsum[threadIdx.x + k * BLK];
  for (int off = 32; off > 0; off >>= 1) val += __shfl_down(val, off);
  __shared__ float wsum[BLK / 64];
  int lane = threadIdx.x & 63;
  int wid = threadIdx.x >> 6;
  if (lane == 0) wsum[wid] = val;
  __syncthreads();
  if (threadIdx.x == 0) {
    float s = 0.0f;
#pragma unroll
    for (int wv = 0; wv < BLK / 64; ++wv) s += wsum[wv];
    out[0] = s * (1.0f / ((float)BB * (float)NN));
  }
}

// Fallback (proven-correct R1 kernel) if ws is too small.
__global__ __launch_bounds__(BLK) void chamfer_bce_kernel(
    const float* __restrict__ est, const float* __restrict__ gt,
    const float* __restrict__ lest, const float* __restrict__ lab,
    float* __restrict__ out) {
  int bid = blockIdx.x;
  int dir = (bid >= BB * (NN / BLK)) ? 1 : 0;
  int id = dir ? (bid - BB * (NN / BLK)) : bid;
  int b = id / (NN / BLK);
  int tile = id % (NN / BLK);
  const float* X = dir ? gt : est;
  const float* Y = dir ? est : gt;
  __shared__ float4 sy[NN];
  const float* yb = Y + (size_t)b * NN * 3;
  for (int j = threadIdx.x; j < NN; j += BLK)
    sy[j] = make_float4(yb[3 * j], yb[3 * j + 1], yb[3 * j + 2], 0.0f);
  __syncthreads();
  int i = tile * BLK + threadIdx.x;
  const float* xb = X + (size_t)b * NN * 3 + (size_t)3 * i;
  float ex = xb[0], ey = xb[1], ez = xb[2];
  float m0 = 3.4e38f, m1 = 3.4e38f, m2 = 3.4e38f, m3 = 3.4e38f;
#pragma unroll 4
  for (int j = 0; j < NN; j += 4) {
    float4 p0 = sy[j], p1 = sy[j + 1], p2 = sy[j + 2], p3 = sy[j + 3];
    { float dx = ex - p0.x, dy = ey - p0.y, dz = ez - p0.z;
      m0 = fminf(m0, fmaf(dx, dx, fmaf(dy, dy, dz * dz))); }
    { float dx = ex - p1.x, dy = ey - p1.y, dz = ez - p1.z;
      m1 = fminf(m1, fmaf(dx, dx, fmaf(dy, dy, dz * dz))); }
    { float dx = ex - p2.x, dy = ey - p2.y, dz = ez - p2.z;
      m2 = fminf(m2, fmaf(dx, dx, fmaf(dy, dy, dz * dz))); }
    { float dx = ex - p3.x, dy = ey - p3.y, dz = ez - p3.z;
      m3 = fminf(m3, fmaf(dx, dx, fmaf(dy, dy, dz * dz))); }
  }
  float val = fminf(fminf(m0, m1), fminf(m2, m3));
  if (!dir) {
    float z = lest[(size_t)b * NN + i];
    float t = lab[(size_t)b * NN + i];
    val += fmaxf(z, 0.0f) - z * t + log1pf(expf(-fabsf(z)));
  }
  for (int off = 32; off > 0; off >>= 1) val += __shfl_down(val, off);
  __shared__ float wsum[BLK / 64];
  int lane = threadIdx.x & 63;
  int wid = threadIdx.x >> 6;
  if (lane == 0) wsum[wid] = val;
  __syncthreads();
  if (threadIdx.x == 0) {
    float s = 0.0f;
#pragma unroll
    for (int w = 0; w < BLK / 64; ++w) s += wsum[w];
    atomicAdd(out, s * (1.0f / ((float)BB * (float)NN)));
  }
}

extern "C" void kernel_launch(void* const* d_in, const int* in_sizes, int n_in,
                              void* d_out, int out_size, void* d_ws, size_t ws_size,
                              hipStream_t stream) {
  const float* est = (const float*)d_in[0];
  const float* gt = (const float*)d_in[1];
  const float* lest = (const float*)d_in[2];
  const float* lab = (const float*)d_in[3];
  float* out = (float*)d_out;

  const size_t need = (size_t)NBLK * sizeof(float);  // 4 KB
  if (ws_size >= need) {
    float* bsum = (float*)d_ws;
    cham_fused<<<dim3(NBLK), dim3(BLK), 0, stream>>>(est, gt, lest, lab, bsum);
    sum_kernel<<<dim3(1), dim3(BLK), 0, stream>>>(bsum, out);
  } else {
    (void)hipMemsetAsync(out, 0, sizeof(float), stream);
    chamfer_bce_kernel<<<dim3(2 * BB * (NN / BLK)), dim3(BLK), 0, stream>>>(
        est, gt, lest, lab, out);
  }
}